// Round 5
// baseline (663.207 us; speedup 1.0000x reference)
//
#include <hip/hip_runtime.h>
#include <hip/hip_bf16.h>

// Problem constants
#define HN 12
#define DHD 64
#define BB 128
#define SQ 197
#define DD 768
#define TOK (BB*SQ)      // 25216 = 128*197
#define SP 224           // padded S for MFMA (attention)
#define SPS 232          // LDS stride in shorts (464B, 16B-aligned)

using short8  = __attribute__((ext_vector_type(8))) short;
using floatx4 = __attribute__((ext_vector_type(4))) float;

__device__ __forceinline__ float bf2f(short v) {
    union { unsigned int u; float f; } x;
    x.u = ((unsigned int)(unsigned short)v) << 16;
    return x.f;
}
__device__ __forceinline__ short f2bf(float f) {
    union { float f; unsigned int u; } x; x.f = f;
    unsigned int u = x.u;
    u += 0x7fffu + ((u >> 16) & 1u);   // RNE
    return (short)(u >> 16);
}
__device__ __forceinline__ float ldf(const void* p, size_t i, bool isf32) {
    return isf32 ? ((const float*)p)[i] : bf2f(((const short*)p)[i]);
}
__device__ __forceinline__ void gload_lds16(const short* g, short* l) {
    __builtin_amdgcn_global_load_lds(
        (const __attribute__((address_space(1))) void*)g,
        (__attribute__((address_space(3))) void*)l, 16, 0, 0);
}

// ---------------------------------------------------------------------------
// Dtype detection: even-index shorts of Wq. bf16 weights have exponents
// ~110..125; f32 low-mantissa halves are ~uniform -> ~50% extreme.
// ---------------------------------------------------------------------------
__global__ __launch_bounds__(256) void detect_kernel(
        const short* __restrict__ wq, float* __restrict__ flag) {
    __shared__ int cnt;
    if (threadIdx.x == 0) cnt = 0;
    __syncthreads();
    int local = 0;
    for (int j = 0; j < 16; j++) {
        int i = threadIdx.x * 16 + j;            // 4096 samples, bytes < 16.4KB
        unsigned int u = (unsigned short)wq[2 * i];
        unsigned int e = (u >> 7) & 0xFF;
        if (e < 64 || e >= 192) local++;
    }
    for (int d = 1; d < 64; d <<= 1) local += __shfl_xor(local, d, 64);
    if ((threadIdx.x & 63) == 0) atomicAdd(&cnt, local);
    __syncthreads();
    if (threadIdx.x == 0) *flag = (cnt > 256) ? 1.f : 0.f;
}

__global__ void sentinel_kernel(short* out, int n, float code) {
    int i = blockIdx.x * 256 + threadIdx.x;
    if (i < n) out[i] = (i == 0) ? f2bf(code) : (short)0;
}

// ---------------------------------------------------------------------------
// Weight prep: transpose + convert Wq/Wk/Wv -> WqkvT[2304][768] bf16,
// Wd -> WdT[768][768] bf16, W1 -> W1T[64][768] bf16; biases -> f32.
// One 64x64 tile per block; blocks 0..575: Wq/Wk/Wv/Wd, 576..587: W1.
// ---------------------------------------------------------------------------
__global__ __launch_bounds__(256) void prep_kernel(
        const void* __restrict__ Wq, const void* __restrict__ Wk,
        const void* __restrict__ Wv, const void* __restrict__ Wd,
        const void* __restrict__ bq, const void* __restrict__ bk,
        const void* __restrict__ bv, const void* __restrict__ bd,
        const void* __restrict__ W1, const void* __restrict__ b1,
        const void* __restrict__ W2, const void* __restrict__ b2,
        short* __restrict__ WqkvT, short* __restrict__ WdT,
        short* __restrict__ W1T, float* __restrict__ bcat,
        const float* __restrict__ flag) {
    __shared__ short tile[64][72];
    bool isf32 = (*flag != 0.f);
    int blk = blockIdx.x;
    int tid = threadIdx.x;
    int r = tid >> 2, c0 = (tid & 3) << 4;
    const void* W;
    size_t stride;
    int ti, tj, w = 0;
    if (blk < 576) {
        w = blk / 144;
        int t = blk % 144;
        ti = t / 12; tj = t % 12;                 // ti: k-tile, tj: n-tile
        W = (w == 0) ? Wq : (w == 1) ? Wk : (w == 2) ? Wv : Wd;
        stride = DD;
    } else {
        ti = blk - 576; tj = 0;
        W = W1;
        stride = 64;
    }
    for (int c = 0; c < 16; c++)
        tile[r][c0 + c] =
            f2bf(ldf(W, (size_t)(ti * 64 + r) * stride + tj * 64 + c0 + c, isf32));
    __syncthreads();
    short* out;
    if (blk < 576)
        out = (w < 3)
            ? WqkvT + ((size_t)(w * DD + tj * 64 + r)) * DD + ti * 64
            : WdT   + ((size_t)(tj * 64 + r)) * DD + ti * 64;
    else
        out = W1T + (size_t)r * DD + ti * 64;
    for (int h = 0; h < 2; h++) {
        short8 v;
        #pragma unroll
        for (int c = 0; c < 8; c++) v[c] = tile[c0 + h * 8 + c][r];
        *(short8*)&out[c0 + h * 8] = v;
    }
    if (blk == 0) {
        for (int i = tid; i < DD; i += 256) {
            bcat[i]          = ldf(bq, i, isf32);
            bcat[DD + i]     = ldf(bk, i, isf32);
            bcat[2 * DD + i] = ldf(bv, i, isf32);
            bcat[3 * DD + i] = ldf(bd, i, isf32);
        }
        if (tid < 64) {
            bcat[4 * DD + tid]      = ldf(b1, tid, isf32);   // b1f
            bcat[4 * DD + 64 + tid] = ldf(W2, tid, isf32);   // w2f
        }
        if (tid == 0) bcat[4 * DD + 128] = ldf(b2, 0, isf32); // b2f
    }
}

// ---------------------------------------------------------------------------
// Scoring MLP as MFMA GEMM, fused with hs -> hsb bf16 conversion.
// ---------------------------------------------------------------------------
__global__ __launch_bounds__(256) void mask_gemm(
        const void* __restrict__ hs, const short* __restrict__ W1T,
        const float* __restrict__ bvec, float* __restrict__ mask,
        short* __restrict__ hsb, const float* __restrict__ flag) {
    __shared__ __align__(16) short As[64 * 32];
    __shared__ __align__(16) short Bs[64 * 32];
    bool isf32 = (*flag != 0.f);
    int tid = threadIdx.x, lane = tid & 63, wave = tid >> 6;
    int quad = lane >> 4, l16 = lane & 15;
    int tok0 = blockIdx.x * 64;

    int arow = tid >> 2, achk = tid & 3;
    int acol = ((achk ^ ((arow >> 1) & 3)) << 3);   // swizzled chunk (shorts)
    const short* Bg = W1T + (size_t)arow * DD +
                      (((achk ^ ((arow >> 1) & 3)) << 3));
    short* Bl = Bs + wave * 512;                    // wave-uniform LDS dest
    int fcol = ((quad ^ ((l16 >> 1) & 3)) << 3);    // fragment read col

    floatx4 acc[4] = {};
    for (int k0 = 0; k0 < DD; k0 += 32) {
        gload_lds16(Bg + k0, Bl);
        size_t gidx = (size_t)(tok0 + arow) * DD + k0 + achk * 8;
        short8 s;
        if (isf32) {
            const float* hf = (const float*)hs;
            float4 f0 = *(const float4*)&hf[gidx];
            float4 f1 = *(const float4*)&hf[gidx + 4];
            s[0]=f2bf(f0.x); s[1]=f2bf(f0.y); s[2]=f2bf(f0.z); s[3]=f2bf(f0.w);
            s[4]=f2bf(f1.x); s[5]=f2bf(f1.y); s[6]=f2bf(f1.z); s[7]=f2bf(f1.w);
        } else {
            s = *(const short8*)&((const short*)hs)[gidx];
        }
        *(short8*)&hsb[gidx] = s;
        *(short8*)&As[(arow << 5) + acol] = s;
        __syncthreads();
        short8 af = *(const short8*)&As[((wave * 16 + l16) << 5) + fcol];
        #pragma unroll
        for (int j = 0; j < 4; j++) {
            short8 bf8 = *(const short8*)&Bs[((j * 16 + l16) << 5) + fcol];
            acc[j] = __builtin_amdgcn_mfma_f32_16x16x32_bf16(af, bf8, acc[j], 0, 0, 0);
        }
        __syncthreads();
    }

    const float* b1f = bvec + 4 * DD;
    const float* w2f = bvec + 4 * DD + 64;
    float b2v = bvec[4 * DD + 128];
    float partial[4] = {0.f, 0.f, 0.f, 0.f};
    #pragma unroll
    for (int j = 0; j < 4; j++) {
        int n = j * 16 + l16;
        float b1v = b1f[n], w2v = w2f[n];
        #pragma unroll
        for (int r = 0; r < 4; r++) {
            float hv = fmaxf(acc[j][r] + b1v, 0.f);
            partial[r] += hv * w2v;
        }
    }
    for (int d = 1; d < 16; d <<= 1)
        #pragma unroll
        for (int r = 0; r < 4; r++)
            partial[r] += __shfl_xor(partial[r], d, 64);
    if (l16 == 0) {
        #pragma unroll
        for (int r = 0; r < 4; r++) {
            int tokr = tok0 + wave * 16 + quad * 4 + r;
            float m = 1.f;
            if (tokr % SQ != 0) {
                float sg = 1.f / (1.f + __expf(-(partial[r] + b2v)));
                m = (sg >= 0.05f) ? 1.f : 0.f;
            }
            mask[tokr] = m;
        }
    }
}

// ---------------------------------------------------------------------------
// 128x64-tile bf16 GEMM, occupancy-first variant: 4 waves, wave = 64x32 out,
// acc = 32 VGPR -> total <=64 VGPR (launch_bounds(256,8)) -> 32 waves/CU.
// BK=32 single LDS buffer (12 KB), 2 barriers/step; latency hidden by TLP.
// Source-side XOR swizzle (gload_lds writes linearly), ds_read_b128 frags.
// MODE 0: C = bf16 [M][N] (QKV).  MODE 1: masked epilogue -> external C.
// ---------------------------------------------------------------------------
template <int MODE>
__global__ __launch_bounds__(256, 8) void gemm128(
        const short* __restrict__ A, const short* __restrict__ BT,
        const float* __restrict__ bias, void* __restrict__ C,
        int m0g, int Mreal, int N,
        const float* __restrict__ mask, const short* __restrict__ resid,
        const void* __restrict__ hs, const float* __restrict__ flag) {
    constexpr int K = DD;
    __shared__ __align__(16) short As[128 * 32];   // 8 KB
    __shared__ __align__(16) short Bs[64 * 32];    // 4 KB
    int tiles_n = N >> 6;
    // bijective XCD-aware swizzle (m204)
    int nwg = gridDim.x, bid = blockIdx.x;
    int qq = nwg >> 3, rr = nwg & 7, xcd = bid & 7, lid = bid >> 3;
    int wg = (xcd < rr ? xcd * (qq + 1) : rr * (qq + 1) + (xcd - rr) * qq) + lid;
    int bm = wg / tiles_n, bn = wg % tiles_n;
    int m0 = bm << 7, n0 = bn << 6;

    int tid = threadIdx.x, lane = tid & 63, wave = tid >> 6;
    int wx = wave & 1, wy = wave >> 1;
    int quad = lane >> 4, l16 = lane & 15;

    // Staging: A has 512 16B-slots, B has 256; slot s holds row=s>>2,
    // k-chunk (s&3)^((row>>1)&3)  (XOR swizzle on the SOURCE side,
    // since global_load_lds writes linearly: base + lane*16).
    int s0 = tid, s1 = 256 + tid;
    int ar0 = s0 >> 2, ac0 = ((s0 & 3) ^ ((ar0 >> 1) & 3)) << 3;
    int ar1 = s1 >> 2, ac1 = ((s1 & 3) ^ ((ar1 >> 1) & 3)) << 3;
    int br  = tid >> 2, bc  = ((tid & 3) ^ ((br >> 1) & 3)) << 3;
    int am0 = m0 + ar0; if (am0 >= Mreal) am0 = Mreal - 1;
    int am1 = m0 + ar1; if (am1 >= Mreal) am1 = Mreal - 1;
    const short* Ag0 = A + (size_t)am0 * K + ac0;
    const short* Ag1 = A + (size_t)am1 * K + ac1;
    const short* Bg  = BT + (size_t)(n0 + br) * K + bc;
    short* Al0 = As + wave * 512;
    short* Al1 = As + 2048 + wave * 512;
    short* Bl  = Bs + wave * 512;

    // fragment read column (same XOR; row bits 1..2 come from l16 only)
    int acol = ((quad ^ ((l16 >> 1) & 3)) << 3);

    floatx4 acc[4][2] = {};
    for (int k0 = 0; k0 < K; k0 += 32) {
        gload_lds16(Ag0 + k0, Al0);
        gload_lds16(Ag1 + k0, Al1);
        gload_lds16(Bg  + k0, Bl);
        __syncthreads();                       // drains vmcnt before barrier
        short8 bfr[2];
        #pragma unroll
        for (int j = 0; j < 2; j++)
            bfr[j] = *(const short8*)&Bs[(((wx << 5) + (j << 4) + l16) << 5) + acol];
        #pragma unroll
        for (int i = 0; i < 4; i++) {
            short8 af = *(const short8*)&As[(((wy << 6) + (i << 4) + l16) << 5) + acol];
            acc[i][0] = __builtin_amdgcn_mfma_f32_16x16x32_bf16(af, bfr[0], acc[i][0], 0, 0, 0);
            acc[i][1] = __builtin_amdgcn_mfma_f32_16x16x32_bf16(af, bfr[1], acc[i][1], 0, 0, 0);
        }
        __syncthreads();                       // reads done before next stage
    }

    bool isf32 = (MODE == 1) ? (*flag != 0.f) : false;
    #pragma unroll
    for (int i = 0; i < 4; i++)
        #pragma unroll
        for (int j = 0; j < 2; j++) {
            int n = n0 + (wx << 5) + (j << 4) + l16;
            float bb = bias[n];
            #pragma unroll
            for (int r = 0; r < 4; r++) {
                int m = m0 + (wy << 6) + (i << 4) + (quad << 2) + r;
                if (m >= Mreal) continue;
                float v = acc[i][j][r] + bb;
                if (MODE == 0) {
                    ((short*)C)[(size_t)m * N + n] = f2bf(v);
                } else {
                    size_t gm = (size_t)(m0g + m);
                    v += bf2f(resid[(size_t)m * N + n]);
                    if (mask[gm] == 0.f) v = ldf(hs, gm * N + n, isf32);
                    if (isf32) ((float*)C)[gm * N + n] = v;
                    else       ((short*)C)[gm * N + n] = f2bf(v);
                }
            }
        }
}

// ---------------------------------------------------------------------------
// Attention: block = (b, h, 64 q-rows); wave = 16 q-rows. Internal bf16.
// XCD-swizzled so the 4 q-chunks (+ heads) of one batch share an XCD L2.
// ---------------------------------------------------------------------------
__global__ __launch_bounds__(256) void attn_kernel(
        const short* __restrict__ qkv, short* __restrict__ ctx) {
    __shared__ __align__(16) short Vt[DHD * SPS];
    __shared__ __align__(16) short P[4 * 16 * SPS];
    int nwg = gridDim.x, bid = blockIdx.x;
    int qq = nwg >> 3, rr = nwg & 7, xcd = bid & 7, lid = bid >> 3;
    int blk = (xcd < rr ? xcd * (qq + 1) : rr * (qq + 1) + (xcd - rr) * qq) + lid;
    int qc = blk & 3;
    int h  = (blk >> 2) % HN;
    int b  = blk / (4 * HN);
    int tid = threadIdx.x, lane = tid & 63, wave = tid >> 6;
    int quad = lane >> 4, l16 = lane & 15;
    const short* base = qkv + (size_t)b * SQ * 2304;

    for (int i = tid; i < SQ * DHD; i += 256) {
        int s = i >> 6, d = i & 63;
        Vt[d * SPS + s] = base[(size_t)s * 2304 + 1536 + h * 64 + d];
    }
    for (int i = tid; i < (SP - SQ) * DHD; i += 256) {
        int s = SQ + i % (SP - SQ), d = i / (SP - SQ);
        Vt[d * SPS + s] = 0;
    }
    __syncthreads();

    int mrow = qc * 64 + wave * 16 + l16;
    if (mrow > SQ - 1) mrow = SQ - 1;
    const short* Qrow = base + (size_t)mrow * 2304 + h * 64;
    short8 aq0 = *(const short8*)(Qrow + quad * 8);
    short8 aq1 = *(const short8*)(Qrow + 32 + quad * 8);

    floatx4 sc[14];
    for (int t = 0; t < 14; t++) {
        int nrow = t * 16 + l16;
        if (nrow > SQ - 1) nrow = SQ - 1;
        const short* Krow = base + (size_t)nrow * 2304 + DD + h * 64;
        short8 b0 = *(const short8*)(Krow + quad * 8);
        short8 b1 = *(const short8*)(Krow + 32 + quad * 8);
        floatx4 c = {0.f, 0.f, 0.f, 0.f};
        c = __builtin_amdgcn_mfma_f32_16x16x32_bf16(aq0, b0, c, 0, 0, 0);
        c = __builtin_amdgcn_mfma_f32_16x16x32_bf16(aq1, b1, c, 0, 0, 0);
        sc[t] = c;
    }

    const float scale = 0.125f;
    float mx[4] = {-1e30f, -1e30f, -1e30f, -1e30f};
    for (int t = 0; t < 14; t++) {
        int col = t * 16 + l16;
        if (col < SQ)
            for (int r = 0; r < 4; r++) mx[r] = fmaxf(mx[r], sc[t][r]);
    }
    for (int d = 1; d < 16; d <<= 1)
        for (int r = 0; r < 4; r++) mx[r] = fmaxf(mx[r], __shfl_xor(mx[r], d, 64));
    float sum[4] = {0.f, 0.f, 0.f, 0.f};
    for (int t = 0; t < 14; t++) {
        int col = t * 16 + l16;
        for (int r = 0; r < 4; r++) {
            float e = (col < SQ) ? __expf((sc[t][r] - mx[r]) * scale) : 0.f;
            sc[t][r] = e; sum[r] += e;
        }
    }
    for (int d = 1; d < 16; d <<= 1)
        for (int r = 0; r < 4; r++) sum[r] += __shfl_xor(sum[r], d, 64);
    float inv[4];
    for (int r = 0; r < 4; r++) inv[r] = 1.f / sum[r];

    short* Pw = &P[wave * 16 * SPS];
    for (int t = 0; t < 14; t++)
        for (int r = 0; r < 4; r++)
            Pw[(quad * 4 + r) * SPS + t * 16 + l16] = f2bf(sc[t][r] * inv[r]);
    __syncthreads();

    floatx4 co[4] = {};
    for (int ks = 0; ks < 7; ks++) {
        short8 pa = *(const short8*)&Pw[l16 * SPS + ks * 32 + quad * 8];
        for (int j = 0; j < 4; j++) {
            short8 vb = *(const short8*)&Vt[(j * 16 + l16) * SPS + ks * 32 + quad * 8];
            co[j] = __builtin_amdgcn_mfma_f32_16x16x32_bf16(pa, vb, co[j], 0, 0, 0);
        }
    }
    int sq0 = qc * 64 + wave * 16 + quad * 4;
    for (int r = 0; r < 4; r++) {
        int s = sq0 + r;
        if (s < SQ) {
            size_t o = ((size_t)(b * SQ + s)) * DD + h * 64;
            for (int j = 0; j < 4; j++)
                ctx[o + j * 16 + l16] = f2bf(co[j][r]);
        }
    }
}

// ---------------------------------------------------------------------------
extern "C" void kernel_launch(void* const* d_in, const int* in_sizes, int n_in,
                              void* d_out, int out_size, void* d_ws, size_t ws_size,
                              hipStream_t stream) {
    const void* hs = d_in[0];
    const void* Wq = d_in[1];
    const void* bq = d_in[2];
    const void* Wk = d_in[3];
    const void* bk = d_in[4];
    const void* Wv = d_in[5];
    const void* bv = d_in[6];
    const void* Wd = d_in[7];
    const void* bd = d_in[8];
    const void* W1 = d_in[9];
    const void* b1 = d_in[10];
    const void* W2 = d_in[11];
    const void* b2 = d_in[12];

    const size_t flag_b  = 16;
    const size_t mask_b  = (size_t)TOK * 4;
    const size_t bcat_b  = (size_t)(4 * DD + 192) * 4;
    const size_t wqkvt_b = (size_t)3 * DD * DD * 2;
    const size_t wdt_b   = (size_t)DD * DD * 2;
    const size_t w1t_b   = (size_t)64 * DD * 2;
    const size_t hsb_b   = (size_t)TOK * DD * 2;
    const size_t fixed   = flag_b + mask_b + bcat_b + wqkvt_b + wdt_b + w1t_b + hsb_b;

    int CHB = 0;
    for (int c = 128; c >= 1; c >>= 1) {
        size_t chtp = (size_t)((c * SQ + 127) / 128) * 128;
        size_t need = fixed + chtp * 2304 * 2 + chtp * DD * 2;
        if (need <= ws_size) { CHB = c; break; }
    }
    if (CHB == 0) {
        sentinel_kernel<<<(out_size + 255) / 256, 256, 0, stream>>>(
            (short*)d_out, out_size, (float)((double)ws_size / 1.0e6));
        return;
    }
    const int CHT  = CHB * SQ;
    const int CHTP = ((CHT + 127) / 128) * 128;

    char* ws = (char*)d_ws;
    float* flag  = (float*)ws;
    float* mask  = (float*)(ws + flag_b);
    float* bcat  = (float*)(ws + flag_b + mask_b);
    short* WqkvT = (short*)(ws + flag_b + mask_b + bcat_b);
    short* WdT   = WqkvT + (size_t)3 * DD * DD;
    short* W1T   = WdT + (size_t)DD * DD;
    short* hsb   = W1T + (size_t)64 * DD;
    short* QKVc  = hsb + (size_t)TOK * DD;
    short* ctxc  = QKVc + (size_t)CHTP * 2304;

    detect_kernel<<<1, 256, 0, stream>>>((const short*)Wq, flag);
    prep_kernel<<<588, 256, 0, stream>>>(Wq, Wk, Wv, Wd, bq, bk, bv, bd,
                                         W1, b1, W2, b2,
                                         WqkvT, WdT, W1T, bcat, flag);
    mask_gemm<<<TOK / 64, 256, 0, stream>>>(hs, W1T, bcat, mask, hsb, flag);

    const int nchunk  = BB / CHB;
    const int tiles_m = CHTP / 128;
    for (int c = 0; c < nchunk; c++) {
        const int m0g = c * CHT;
        gemm128<0><<<tiles_m * (3 * DD / 64), 256, 0, stream>>>(
            hsb + (size_t)m0g * DD, WqkvT, bcat, QKVc,
            m0g, CHT, 3 * DD, nullptr, nullptr, nullptr, flag);
        attn_kernel<<<CHB * HN * 4, 256, 0, stream>>>(QKVc, ctxc);
        gemm128<1><<<tiles_m * (DD / 64), 256, 0, stream>>>(
            ctxc, WdT, bcat + 3 * DD, d_out,
            m0g, CHT, DD, mask, ctxc, hs, flag);
    }
}

// Round 6
// 560.374 us; speedup vs baseline: 1.1835x; 1.1835x over previous
//
#include <hip/hip_runtime.h>
#include <hip/hip_bf16.h>

// Problem constants
#define HN 12
#define DHD 64
#define BB 128
#define SQ 197
#define DD 768
#define TOK (BB*SQ)      // 25216 = 128*197
#define SP 224           // padded S for MFMA (attention)
#define SPS 232          // LDS stride in shorts (464B, 16B-aligned)

using short8  = __attribute__((ext_vector_type(8))) short;
using floatx4 = __attribute__((ext_vector_type(4))) float;

__device__ __forceinline__ float bf2f(short v) {
    union { unsigned int u; float f; } x;
    x.u = ((unsigned int)(unsigned short)v) << 16;
    return x.f;
}
__device__ __forceinline__ short f2bf(float f) {
    union { float f; unsigned int u; } x; x.f = f;
    unsigned int u = x.u;
    u += 0x7fffu + ((u >> 16) & 1u);   // RNE
    return (short)(u >> 16);
}
__device__ __forceinline__ float ldf(const void* p, size_t i, bool isf32) {
    return isf32 ? ((const float*)p)[i] : bf2f(((const short*)p)[i]);
}
__device__ __forceinline__ void gload_lds16(const short* g, short* l) {
    __builtin_amdgcn_global_load_lds(
        (const __attribute__((address_space(1))) void*)g,
        (__attribute__((address_space(3))) void*)l, 16, 0, 0);
}

// ---------------------------------------------------------------------------
// Dtype detection: even-index shorts of Wq. bf16 weights have exponents
// ~110..125; f32 low-mantissa halves are ~uniform -> ~50% extreme.
// ---------------------------------------------------------------------------
__global__ __launch_bounds__(256) void detect_kernel(
        const short* __restrict__ wq, float* __restrict__ flag) {
    __shared__ int cnt;
    if (threadIdx.x == 0) cnt = 0;
    __syncthreads();
    int local = 0;
    for (int j = 0; j < 16; j++) {
        int i = threadIdx.x * 16 + j;            // 4096 samples, bytes < 16.4KB
        unsigned int u = (unsigned short)wq[2 * i];
        unsigned int e = (u >> 7) & 0xFF;
        if (e < 64 || e >= 192) local++;
    }
    for (int d = 1; d < 64; d <<= 1) local += __shfl_xor(local, d, 64);
    if ((threadIdx.x & 63) == 0) atomicAdd(&cnt, local);
    __syncthreads();
    if (threadIdx.x == 0) *flag = (cnt > 256) ? 1.f : 0.f;
}

__global__ void sentinel_kernel(short* out, int n, float code) {
    int i = blockIdx.x * 256 + threadIdx.x;
    if (i < n) out[i] = (i == 0) ? f2bf(code) : (short)0;
}

// ---------------------------------------------------------------------------
// Weight prep: transpose + convert Wq/Wk/Wv -> WqkvT[2304][768] bf16,
// Wd -> WdT[768][768] bf16, W1 -> W1T[64][768] bf16; biases -> f32.
// One 64x64 tile per block; blocks 0..575: Wq/Wk/Wv/Wd, 576..587: W1.
// ---------------------------------------------------------------------------
__global__ __launch_bounds__(256) void prep_kernel(
        const void* __restrict__ Wq, const void* __restrict__ Wk,
        const void* __restrict__ Wv, const void* __restrict__ Wd,
        const void* __restrict__ bq, const void* __restrict__ bk,
        const void* __restrict__ bv, const void* __restrict__ bd,
        const void* __restrict__ W1, const void* __restrict__ b1,
        const void* __restrict__ W2, const void* __restrict__ b2,
        short* __restrict__ WqkvT, short* __restrict__ WdT,
        short* __restrict__ W1T, float* __restrict__ bcat,
        const float* __restrict__ flag) {
    __shared__ short tile[64][72];
    bool isf32 = (*flag != 0.f);
    int blk = blockIdx.x;
    int tid = threadIdx.x;
    int r = tid >> 2, c0 = (tid & 3) << 4;
    const void* W;
    size_t stride;
    int ti, tj, w = 0;
    if (blk < 576) {
        w = blk / 144;
        int t = blk % 144;
        ti = t / 12; tj = t % 12;                 // ti: k-tile, tj: n-tile
        W = (w == 0) ? Wq : (w == 1) ? Wk : (w == 2) ? Wv : Wd;
        stride = DD;
    } else {
        ti = blk - 576; tj = 0;
        W = W1;
        stride = 64;
    }
    for (int c = 0; c < 16; c++)
        tile[r][c0 + c] =
            f2bf(ldf(W, (size_t)(ti * 64 + r) * stride + tj * 64 + c0 + c, isf32));
    __syncthreads();
    short* out;
    if (blk < 576)
        out = (w < 3)
            ? WqkvT + ((size_t)(w * DD + tj * 64 + r)) * DD + ti * 64
            : WdT   + ((size_t)(tj * 64 + r)) * DD + ti * 64;
    else
        out = W1T + (size_t)r * DD + ti * 64;
    for (int h = 0; h < 2; h++) {
        short8 v;
        #pragma unroll
        for (int c = 0; c < 8; c++) v[c] = tile[c0 + h * 8 + c][r];
        *(short8*)&out[c0 + h * 8] = v;
    }
    if (blk == 0) {
        for (int i = tid; i < DD; i += 256) {
            bcat[i]          = ldf(bq, i, isf32);
            bcat[DD + i]     = ldf(bk, i, isf32);
            bcat[2 * DD + i] = ldf(bv, i, isf32);
            bcat[3 * DD + i] = ldf(bd, i, isf32);
        }
        if (tid < 64) {
            bcat[4 * DD + tid]      = ldf(b1, tid, isf32);   // b1f
            bcat[4 * DD + 64 + tid] = ldf(W2, tid, isf32);   // w2f
        }
        if (tid == 0) bcat[4 * DD + 128] = ldf(b2, 0, isf32); // b2f
    }
}

// ---------------------------------------------------------------------------
// Scoring MLP as MFMA GEMM, fused with hs -> hsb bf16 conversion.
// ---------------------------------------------------------------------------
__global__ __launch_bounds__(256) void mask_gemm(
        const void* __restrict__ hs, const short* __restrict__ W1T,
        const float* __restrict__ bvec, float* __restrict__ mask,
        short* __restrict__ hsb, const float* __restrict__ flag) {
    __shared__ __align__(16) short As[64 * 32];
    __shared__ __align__(16) short Bs[64 * 32];
    bool isf32 = (*flag != 0.f);
    int tid = threadIdx.x, lane = tid & 63, wave = tid >> 6;
    int quad = lane >> 4, l16 = lane & 15;
    int tok0 = blockIdx.x * 64;

    int arow = tid >> 2, achk = tid & 3;
    int acol = ((achk ^ ((arow >> 1) & 3)) << 3);   // swizzled chunk (shorts)
    const short* Bg = W1T + (size_t)arow * DD +
                      (((achk ^ ((arow >> 1) & 3)) << 3));
    short* Bl = Bs + wave * 512;                    // wave-uniform LDS dest
    int fcol = ((quad ^ ((l16 >> 1) & 3)) << 3);    // fragment read col

    floatx4 acc[4] = {};
    for (int k0 = 0; k0 < DD; k0 += 32) {
        gload_lds16(Bg + k0, Bl);
        size_t gidx = (size_t)(tok0 + arow) * DD + k0 + achk * 8;
        short8 s;
        if (isf32) {
            const float* hf = (const float*)hs;
            float4 f0 = *(const float4*)&hf[gidx];
            float4 f1 = *(const float4*)&hf[gidx + 4];
            s[0]=f2bf(f0.x); s[1]=f2bf(f0.y); s[2]=f2bf(f0.z); s[3]=f2bf(f0.w);
            s[4]=f2bf(f1.x); s[5]=f2bf(f1.y); s[6]=f2bf(f1.z); s[7]=f2bf(f1.w);
        } else {
            s = *(const short8*)&((const short*)hs)[gidx];
        }
        *(short8*)&hsb[gidx] = s;
        *(short8*)&As[(arow << 5) + acol] = s;
        __syncthreads();
        short8 af = *(const short8*)&As[((wave * 16 + l16) << 5) + fcol];
        #pragma unroll
        for (int j = 0; j < 4; j++) {
            short8 bf8 = *(const short8*)&Bs[((j * 16 + l16) << 5) + fcol];
            acc[j] = __builtin_amdgcn_mfma_f32_16x16x32_bf16(af, bf8, acc[j], 0, 0, 0);
        }
        __syncthreads();
    }

    const float* b1f = bvec + 4 * DD;
    const float* w2f = bvec + 4 * DD + 64;
    float b2v = bvec[4 * DD + 128];
    float partial[4] = {0.f, 0.f, 0.f, 0.f};
    #pragma unroll
    for (int j = 0; j < 4; j++) {
        int n = j * 16 + l16;
        float b1v = b1f[n], w2v = w2f[n];
        #pragma unroll
        for (int r = 0; r < 4; r++) {
            float hv = fmaxf(acc[j][r] + b1v, 0.f);
            partial[r] += hv * w2v;
        }
    }
    for (int d = 1; d < 16; d <<= 1)
        #pragma unroll
        for (int r = 0; r < 4; r++)
            partial[r] += __shfl_xor(partial[r], d, 64);
    if (l16 == 0) {
        #pragma unroll
        for (int r = 0; r < 4; r++) {
            int tokr = tok0 + wave * 16 + quad * 4 + r;
            float m = 1.f;
            if (tokr % SQ != 0) {
                float sg = 1.f / (1.f + __expf(-(partial[r] + b2v)));
                m = (sg >= 0.05f) ? 1.f : 0.f;
            }
            mask[tokr] = m;
        }
    }
}

// ---------------------------------------------------------------------------
// 128x128-tile bf16 GEMM, 8 waves (512 thr), per-wave 64x32 out (acc=32 reg).
// BK=64, single LDS buffer (32 KB), 12 K-steps -> half the barrier drains.
// Total regs ~80 -> 16 waves/CU (2 blocks) via __launch_bounds__(512,4).
// Source-side XOR swizzle over 8 chunks/row (gload_lds writes linearly),
// ds_read_b128 fragments, conflict-free per 16-lane phase.
// MODE 0: C = bf16 [M][N] (QKV).  MODE 1: masked epilogue -> external C.
// ---------------------------------------------------------------------------
template <int MODE>
__global__ __launch_bounds__(512, 4) void gemm128(
        const short* __restrict__ A, const short* __restrict__ BT,
        const float* __restrict__ bias, void* __restrict__ C,
        int m0g, int Mreal, int N,
        const float* __restrict__ mask, const short* __restrict__ resid,
        const void* __restrict__ hs, const float* __restrict__ flag) {
    constexpr int K = DD;
    constexpr int BK = 64;
    __shared__ __align__(16) short As[128 * BK];   // 16 KB
    __shared__ __align__(16) short Bs[128 * BK];   // 16 KB
    int tiles_n = N >> 7;
    // bijective XCD-aware swizzle (m204)
    int nwg = gridDim.x, bid = blockIdx.x;
    int qq = nwg >> 3, rr = nwg & 7, xcd = bid & 7, lid = bid >> 3;
    int wg = (xcd < rr ? xcd * (qq + 1) : rr * (qq + 1) + (xcd - rr) * qq) + lid;
    int bm = wg / tiles_n, bn = wg % tiles_n;
    int m0 = bm << 7, n0 = bn << 7;

    int tid = threadIdx.x, lane = tid & 63, wave = tid >> 6;   // 8 waves
    int wx = wave & 3, wy = wave >> 2;        // 4 n-waves x 2 m-waves
    int quad = lane >> 4, l16 = lane & 15, l7 = l16 & 7;

    // Staging: each matrix = 1024 16B-slots (128 rows x 8 chunks).
    // Wave w, inst i covers slots [w*128 + i*64, +64): slot s -> row s>>3,
    // chunk s&7; source col = ((s&7) ^ (row&7))*8 shorts (XOR swizzle on the
    // SOURCE side since global_load_lds writes linearly: base + lane*16).
    int slot0 = (wave << 7) + lane;
    int slot1 = slot0 + 64;
    int r0 = slot0 >> 3, c0s = ((slot0 & 7) ^ (r0 & 7)) << 3;
    int r1 = slot1 >> 3, c1s = ((slot1 & 7) ^ (r1 & 7)) << 3;
    int am0 = m0 + r0; if (am0 >= Mreal) am0 = Mreal - 1;
    int am1 = m0 + r1; if (am1 >= Mreal) am1 = Mreal - 1;
    const short* Ag0 = A + (size_t)am0 * K + c0s;
    const short* Ag1 = A + (size_t)am1 * K + c1s;
    const short* Bg0 = BT + (size_t)(n0 + r0) * K + c0s;
    const short* Bg1 = BT + (size_t)(n0 + r1) * K + c1s;
    short* Al0 = As + wave * 1024;             // slot*8 shorts
    short* Al1 = Al0 + 512;
    short* Bl0 = Bs + wave * 1024;
    short* Bl1 = Bl0 + 512;

    floatx4 acc[4][2] = {};
    for (int k0 = 0; k0 < K; k0 += BK) {
        gload_lds16(Ag0 + k0, Al0);
        gload_lds16(Ag1 + k0, Al1);
        gload_lds16(Bg0 + k0, Bl0);
        gload_lds16(Bg1 + k0, Bl1);
        __syncthreads();                       // drains vmcnt before barrier
        #pragma unroll
        for (int ks = 0; ks < 2; ks++) {
            int colo = ((((ks << 2) + quad) ^ l7) << 3);
            short8 af[4], bfr[2];
            #pragma unroll
            for (int i = 0; i < 4; i++)
                af[i] = *(const short8*)&As[(((wy << 6) + (i << 4) + l16) << 6) + colo];
            #pragma unroll
            for (int j = 0; j < 2; j++)
                bfr[j] = *(const short8*)&Bs[(((wx << 5) + (j << 4) + l16) << 6) + colo];
            #pragma unroll
            for (int i = 0; i < 4; i++)
                #pragma unroll
                for (int j = 0; j < 2; j++)
                    acc[i][j] = __builtin_amdgcn_mfma_f32_16x16x32_bf16(
                        af[i], bfr[j], acc[i][j], 0, 0, 0);
        }
        __syncthreads();                       // reads done before next stage
    }

    bool isf32 = (MODE == 1) ? (*flag != 0.f) : false;
    #pragma unroll
    for (int i = 0; i < 4; i++)
        #pragma unroll
        for (int j = 0; j < 2; j++) {
            int n = n0 + (wx << 5) + (j << 4) + l16;
            float bb = bias[n];
            #pragma unroll
            for (int r = 0; r < 4; r++) {
                int m = m0 + (wy << 6) + (i << 4) + (quad << 2) + r;
                if (m >= Mreal) continue;
                float v = acc[i][j][r] + bb;
                if (MODE == 0) {
                    ((short*)C)[(size_t)m * N + n] = f2bf(v);
                } else {
                    size_t gm = (size_t)(m0g + m);
                    v += bf2f(resid[(size_t)m * N + n]);
                    if (mask[gm] == 0.f) v = ldf(hs, gm * N + n, isf32);
                    if (isf32) ((float*)C)[gm * N + n] = v;
                    else       ((short*)C)[gm * N + n] = f2bf(v);
                }
            }
        }
}

// ---------------------------------------------------------------------------
// Attention: block = (b, h, 64 q-rows); wave = 16 q-rows. Internal bf16.
// XCD-swizzled so the 4 q-chunks (+ heads) of one batch share an XCD L2.
// ---------------------------------------------------------------------------
__global__ __launch_bounds__(256) void attn_kernel(
        const short* __restrict__ qkv, short* __restrict__ ctx) {
    __shared__ __align__(16) short Vt[DHD * SPS];
    __shared__ __align__(16) short P[4 * 16 * SPS];
    int nwg = gridDim.x, bid = blockIdx.x;
    int qq = nwg >> 3, rr = nwg & 7, xcd = bid & 7, lid = bid >> 3;
    int blk = (xcd < rr ? xcd * (qq + 1) : rr * (qq + 1) + (xcd - rr) * qq) + lid;
    int qc = blk & 3;
    int h  = (blk >> 2) % HN;
    int b  = blk / (4 * HN);
    int tid = threadIdx.x, lane = tid & 63, wave = tid >> 6;
    int quad = lane >> 4, l16 = lane & 15;
    const short* base = qkv + (size_t)b * SQ * 2304;

    for (int i = tid; i < SQ * DHD; i += 256) {
        int s = i >> 6, d = i & 63;
        Vt[d * SPS + s] = base[(size_t)s * 2304 + 1536 + h * 64 + d];
    }
    for (int i = tid; i < (SP - SQ) * DHD; i += 256) {
        int s = SQ + i % (SP - SQ), d = i / (SP - SQ);
        Vt[d * SPS + s] = 0;
    }
    __syncthreads();

    int mrow = qc * 64 + wave * 16 + l16;
    if (mrow > SQ - 1) mrow = SQ - 1;
    const short* Qrow = base + (size_t)mrow * 2304 + h * 64;
    short8 aq0 = *(const short8*)(Qrow + quad * 8);
    short8 aq1 = *(const short8*)(Qrow + 32 + quad * 8);

    floatx4 sc[14];
    for (int t = 0; t < 14; t++) {
        int nrow = t * 16 + l16;
        if (nrow > SQ - 1) nrow = SQ - 1;
        const short* Krow = base + (size_t)nrow * 2304 + DD + h * 64;
        short8 b0 = *(const short8*)(Krow + quad * 8);
        short8 b1 = *(const short8*)(Krow + 32 + quad * 8);
        floatx4 c = {0.f, 0.f, 0.f, 0.f};
        c = __builtin_amdgcn_mfma_f32_16x16x32_bf16(aq0, b0, c, 0, 0, 0);
        c = __builtin_amdgcn_mfma_f32_16x16x32_bf16(aq1, b1, c, 0, 0, 0);
        sc[t] = c;
    }

    const float scale = 0.125f;
    float mx[4] = {-1e30f, -1e30f, -1e30f, -1e30f};
    for (int t = 0; t < 14; t++) {
        int col = t * 16 + l16;
        if (col < SQ)
            for (int r = 0; r < 4; r++) mx[r] = fmaxf(mx[r], sc[t][r]);
    }
    for (int d = 1; d < 16; d <<= 1)
        for (int r = 0; r < 4; r++) mx[r] = fmaxf(mx[r], __shfl_xor(mx[r], d, 64));
    float sum[4] = {0.f, 0.f, 0.f, 0.f};
    for (int t = 0; t < 14; t++) {
        int col = t * 16 + l16;
        for (int r = 0; r < 4; r++) {
            float e = (col < SQ) ? __expf((sc[t][r] - mx[r]) * scale) : 0.f;
            sc[t][r] = e; sum[r] += e;
        }
    }
    for (int d = 1; d < 16; d <<= 1)
        for (int r = 0; r < 4; r++) sum[r] += __shfl_xor(sum[r], d, 64);
    float inv[4];
    for (int r = 0; r < 4; r++) inv[r] = 1.f / sum[r];

    short* Pw = &P[wave * 16 * SPS];
    for (int t = 0; t < 14; t++)
        for (int r = 0; r < 4; r++)
            Pw[(quad * 4 + r) * SPS + t * 16 + l16] = f2bf(sc[t][r] * inv[r]);
    __syncthreads();

    floatx4 co[4] = {};
    for (int ks = 0; ks < 7; ks++) {
        short8 pa = *(const short8*)&Pw[l16 * SPS + ks * 32 + quad * 8];
        for (int j = 0; j < 4; j++) {
            short8 vb = *(const short8*)&Vt[(j * 16 + l16) * SPS + ks * 32 + quad * 8];
            co[j] = __builtin_amdgcn_mfma_f32_16x16x32_bf16(pa, vb, co[j], 0, 0, 0);
        }
    }
    int sq0 = qc * 64 + wave * 16 + quad * 4;
    for (int r = 0; r < 4; r++) {
        int s = sq0 + r;
        if (s < SQ) {
            size_t o = ((size_t)(b * SQ + s)) * DD + h * 64;
            for (int j = 0; j < 4; j++)
                ctx[o + j * 16 + l16] = f2bf(co[j][r]);
        }
    }
}

// ---------------------------------------------------------------------------
extern "C" void kernel_launch(void* const* d_in, const int* in_sizes, int n_in,
                              void* d_out, int out_size, void* d_ws, size_t ws_size,
                              hipStream_t stream) {
    const void* hs = d_in[0];
    const void* Wq = d_in[1];
    const void* bq = d_in[2];
    const void* Wk = d_in[3];
    const void* bk = d_in[4];
    const void* Wv = d_in[5];
    const void* bv = d_in[6];
    const void* Wd = d_in[7];
    const void* bd = d_in[8];
    const void* W1 = d_in[9];
    const void* b1 = d_in[10];
    const void* W2 = d_in[11];
    const void* b2 = d_in[12];

    const size_t flag_b  = 16;
    const size_t mask_b  = (size_t)TOK * 4;
    const size_t bcat_b  = (size_t)(4 * DD + 192) * 4;
    const size_t wqkvt_b = (size_t)3 * DD * DD * 2;
    const size_t wdt_b   = (size_t)DD * DD * 2;
    const size_t w1t_b   = (size_t)64 * DD * 2;
    const size_t hsb_b   = (size_t)TOK * DD * 2;
    const size_t fixed   = flag_b + mask_b + bcat_b + wqkvt_b + wdt_b + w1t_b + hsb_b;

    int CHB = 0;
    for (int c = 128; c >= 1; c >>= 1) {
        size_t chtp = (size_t)((c * SQ + 127) / 128) * 128;
        size_t need = fixed + chtp * 2304 * 2 + chtp * DD * 2;
        if (need <= ws_size) { CHB = c; break; }
    }
    if (CHB == 0) {
        sentinel_kernel<<<(out_size + 255) / 256, 256, 0, stream>>>(
            (short*)d_out, out_size, (float)((double)ws_size / 1.0e6));
        return;
    }
    const int CHT  = CHB * SQ;
    const int CHTP = ((CHT + 127) / 128) * 128;

    char* ws = (char*)d_ws;
    float* flag  = (float*)ws;
    float* mask  = (float*)(ws + flag_b);
    float* bcat  = (float*)(ws + flag_b + mask_b);
    short* WqkvT = (short*)(ws + flag_b + mask_b + bcat_b);
    short* WdT   = WqkvT + (size_t)3 * DD * DD;
    short* W1T   = WdT + (size_t)DD * DD;
    short* hsb   = W1T + (size_t)64 * DD;
    short* QKVc  = hsb + (size_t)TOK * DD;
    short* ctxc  = QKVc + (size_t)CHTP * 2304;

    detect_kernel<<<1, 256, 0, stream>>>((const short*)Wq, flag);
    prep_kernel<<<588, 256, 0, stream>>>(Wq, Wk, Wv, Wd, bq, bk, bv, bd,
                                         W1, b1, W2, b2,
                                         WqkvT, WdT, W1T, bcat, flag);
    mask_gemm<<<TOK / 64, 256, 0, stream>>>(hs, W1T, bcat, mask, hsb, flag);

    const int nchunk  = BB / CHB;
    const int tiles_m = CHTP / 128;
    for (int c = 0; c < nchunk; c++) {
        const int m0g = c * CHT;
        gemm128<0><<<tiles_m * (3 * DD / 128), 512, 0, stream>>>(
            hsb + (size_t)m0g * DD, WqkvT, bcat, QKVc,
            m0g, CHT, 3 * DD, nullptr, nullptr, nullptr, flag);
        attn_kernel<<<CHB * HN * 4, 256, 0, stream>>>(QKVc, ctxc);
        gemm128<1><<<tiles_m * (DD / 128), 512, 0, stream>>>(
            ctxc, WdT, bcat + 3 * DD, d_out,
            m0g, CHT, DD, mask, ctxc, hs, flag);
    }
}

// Round 7
// 530.998 us; speedup vs baseline: 1.2490x; 1.0553x over previous
//
#include <hip/hip_runtime.h>
#include <hip/hip_bf16.h>

// Problem constants
#define HN 12
#define DHD 64
#define BB 128
#define SQ 197
#define DD 768
#define TOK (BB*SQ)      // 25216 = 128*197
#define SP 224           // padded S for MFMA (attention)
#define SPS 232          // LDS stride in shorts (464B, 16B-aligned)

using short8  = __attribute__((ext_vector_type(8))) short;
using floatx4 = __attribute__((ext_vector_type(4))) float;
using uintx4  = __attribute__((ext_vector_type(4))) unsigned;
using uintx2  = __attribute__((ext_vector_type(2))) unsigned;

__device__ __forceinline__ float bf2f(short v) {
    union { unsigned int u; float f; } x;
    x.u = ((unsigned int)(unsigned short)v) << 16;
    return x.f;
}
__device__ __forceinline__ short f2bf(float f) {
    union { float f; unsigned int u; } x; x.f = f;
    unsigned int u = x.u;
    u += 0x7fffu + ((u >> 16) & 1u);   // RNE
    return (short)(u >> 16);
}
__device__ __forceinline__ float ldf(const void* p, size_t i, bool isf32) {
    return isf32 ? ((const float*)p)[i] : bf2f(((const short*)p)[i]);
}
__device__ __forceinline__ void gload_lds16(const short* g, short* l) {
    __builtin_amdgcn_global_load_lds(
        (const __attribute__((address_space(1))) void*)g,
        (__attribute__((address_space(3))) void*)l, 16, 0, 0);
}
// packed f32x2 -> bf16x2 (RNE); no builtin on gfx950 -> inline asm
__device__ __forceinline__ unsigned cvtpk(float lo, float hi) {
    unsigned r;
    asm volatile("v_cvt_pk_bf16_f32 %0, %1, %2" : "=v"(r) : "v"(lo), "v"(hi));
    return r;
}

// ---------------------------------------------------------------------------
// Dtype detection: even-index shorts of Wq. bf16 weights have exponents
// ~110..125; f32 low-mantissa halves are ~uniform -> ~50% extreme.
// ---------------------------------------------------------------------------
__global__ __launch_bounds__(256) void detect_kernel(
        const short* __restrict__ wq, float* __restrict__ flag) {
    __shared__ int cnt;
    if (threadIdx.x == 0) cnt = 0;
    __syncthreads();
    int local = 0;
    for (int j = 0; j < 16; j++) {
        int i = threadIdx.x * 16 + j;            // 4096 samples, bytes < 16.4KB
        unsigned int u = (unsigned short)wq[2 * i];
        unsigned int e = (u >> 7) & 0xFF;
        if (e < 64 || e >= 192) local++;
    }
    for (int d = 1; d < 64; d <<= 1) local += __shfl_xor(local, d, 64);
    if ((threadIdx.x & 63) == 0) atomicAdd(&cnt, local);
    __syncthreads();
    if (threadIdx.x == 0) *flag = (cnt > 256) ? 1.f : 0.f;
}

__global__ void sentinel_kernel(short* out, int n, float code) {
    int i = blockIdx.x * 256 + threadIdx.x;
    if (i < n) out[i] = (i == 0) ? f2bf(code) : (short)0;
}

// ---------------------------------------------------------------------------
// Weight prep: transpose + convert Wq/Wk/Wv -> WqkvT[2304][768] bf16,
// Wd -> WdT[768][768] bf16, W1 -> W1T[64][768] bf16; biases -> f32.
// One 64x64 tile per block; blocks 0..575: Wq/Wk/Wv/Wd, 576..587: W1.
// ---------------------------------------------------------------------------
__global__ __launch_bounds__(256) void prep_kernel(
        const void* __restrict__ Wq, const void* __restrict__ Wk,
        const void* __restrict__ Wv, const void* __restrict__ Wd,
        const void* __restrict__ bq, const void* __restrict__ bk,
        const void* __restrict__ bv, const void* __restrict__ bd,
        const void* __restrict__ W1, const void* __restrict__ b1,
        const void* __restrict__ W2, const void* __restrict__ b2,
        short* __restrict__ WqkvT, short* __restrict__ WdT,
        short* __restrict__ W1T, float* __restrict__ bcat,
        const float* __restrict__ flag) {
    __shared__ short tile[64][72];
    bool isf32 = (*flag != 0.f);
    int blk = blockIdx.x;
    int tid = threadIdx.x;
    int r = tid >> 2, c0 = (tid & 3) << 4;
    const void* W;
    size_t stride;
    int ti, tj, w = 0;
    if (blk < 576) {
        w = blk / 144;
        int t = blk % 144;
        ti = t / 12; tj = t % 12;                 // ti: k-tile, tj: n-tile
        W = (w == 0) ? Wq : (w == 1) ? Wk : (w == 2) ? Wv : Wd;
        stride = DD;
    } else {
        ti = blk - 576; tj = 0;
        W = W1;
        stride = 64;
    }
    for (int c = 0; c < 16; c++)
        tile[r][c0 + c] =
            f2bf(ldf(W, (size_t)(ti * 64 + r) * stride + tj * 64 + c0 + c, isf32));
    __syncthreads();
    short* out;
    if (blk < 576)
        out = (w < 3)
            ? WqkvT + ((size_t)(w * DD + tj * 64 + r)) * DD + ti * 64
            : WdT   + ((size_t)(tj * 64 + r)) * DD + ti * 64;
    else
        out = W1T + (size_t)r * DD + ti * 64;
    for (int h = 0; h < 2; h++) {
        short8 v;
        #pragma unroll
        for (int c = 0; c < 8; c++) v[c] = tile[c0 + h * 8 + c][r];
        *(short8*)&out[c0 + h * 8] = v;
    }
    if (blk == 0) {
        for (int i = tid; i < DD; i += 256) {
            bcat[i]          = ldf(bq, i, isf32);
            bcat[DD + i]     = ldf(bk, i, isf32);
            bcat[2 * DD + i] = ldf(bv, i, isf32);
            bcat[3 * DD + i] = ldf(bd, i, isf32);
        }
        if (tid < 64) {
            bcat[4 * DD + tid]      = ldf(b1, tid, isf32);   // b1f
            bcat[4 * DD + 64 + tid] = ldf(W2, tid, isf32);   // w2f
        }
        if (tid == 0) bcat[4 * DD + 128] = ldf(b2, 0, isf32); // b2f
    }
}

// ---------------------------------------------------------------------------
// Scoring MLP as MFMA GEMM, fused with hs -> hsb bf16 conversion.
// ---------------------------------------------------------------------------
__global__ __launch_bounds__(256) void mask_gemm(
        const void* __restrict__ hs, const short* __restrict__ W1T,
        const float* __restrict__ bvec, float* __restrict__ mask,
        short* __restrict__ hsb, const float* __restrict__ flag) {
    __shared__ __align__(16) short As[64 * 32];
    __shared__ __align__(16) short Bs[64 * 32];
    bool isf32 = (*flag != 0.f);
    int tid = threadIdx.x, lane = tid & 63, wave = tid >> 6;
    int quad = lane >> 4, l16 = lane & 15;
    int tok0 = blockIdx.x * 64;

    int arow = tid >> 2, achk = tid & 3;
    int acol = ((achk ^ ((arow >> 1) & 3)) << 3);   // swizzled chunk (shorts)
    const short* Bg = W1T + (size_t)arow * DD +
                      (((achk ^ ((arow >> 1) & 3)) << 3));
    short* Bl = Bs + wave * 512;                    // wave-uniform LDS dest
    int fcol = ((quad ^ ((l16 >> 1) & 3)) << 3);    // fragment read col

    floatx4 acc[4] = {};
    for (int k0 = 0; k0 < DD; k0 += 32) {
        gload_lds16(Bg + k0, Bl);
        size_t gidx = (size_t)(tok0 + arow) * DD + k0 + achk * 8;
        short8 s;
        if (isf32) {
            const float* hf = (const float*)hs;
            float4 f0 = *(const float4*)&hf[gidx];
            float4 f1 = *(const float4*)&hf[gidx + 4];
            s[0]=f2bf(f0.x); s[1]=f2bf(f0.y); s[2]=f2bf(f0.z); s[3]=f2bf(f0.w);
            s[4]=f2bf(f1.x); s[5]=f2bf(f1.y); s[6]=f2bf(f1.z); s[7]=f2bf(f1.w);
        } else {
            s = *(const short8*)&((const short*)hs)[gidx];
        }
        *(short8*)&hsb[gidx] = s;
        *(short8*)&As[(arow << 5) + acol] = s;
        __syncthreads();
        short8 af = *(const short8*)&As[((wave * 16 + l16) << 5) + fcol];
        #pragma unroll
        for (int j = 0; j < 4; j++) {
            short8 bf8 = *(const short8*)&Bs[((j * 16 + l16) << 5) + fcol];
            acc[j] = __builtin_amdgcn_mfma_f32_16x16x32_bf16(af, bf8, acc[j], 0, 0, 0);
        }
        __syncthreads();
    }

    const float* b1f = bvec + 4 * DD;
    const float* w2f = bvec + 4 * DD + 64;
    float b2v = bvec[4 * DD + 128];
    float partial[4] = {0.f, 0.f, 0.f, 0.f};
    #pragma unroll
    for (int j = 0; j < 4; j++) {
        int n = j * 16 + l16;
        float b1v = b1f[n], w2v = w2f[n];
        #pragma unroll
        for (int r = 0; r < 4; r++) {
            float hv = fmaxf(acc[j][r] + b1v, 0.f);
            partial[r] += hv * w2v;
        }
    }
    for (int d = 1; d < 16; d <<= 1)
        #pragma unroll
        for (int r = 0; r < 4; r++)
            partial[r] += __shfl_xor(partial[r], d, 64);
    if (l16 == 0) {
        #pragma unroll
        for (int r = 0; r < 4; r++) {
            int tokr = tok0 + wave * 16 + quad * 4 + r;
            float m = 1.f;
            if (tokr % SQ != 0) {
                float sg = 1.f / (1.f + __expf(-(partial[r] + b2v)));
                m = (sg >= 0.05f) ? 1.f : 0.f;
            }
            mask[tokr] = m;
        }
    }
}

// ---------------------------------------------------------------------------
// 128x128-tile bf16 GEMM, 8 waves (512 thr), per-wave 64x32 out (acc=32 reg).
// BK=64, single LDS buffer (32 KB), 12 K-steps -> half the barrier drains.
// Source-side XOR swizzle over 8 chunks/row (gload_lds writes linearly),
// ds_read_b128 fragments, conflict-free per 16-lane phase.
// MODE 0: C = bf16 [M][N] (QKV).  MODE 1: masked epilogue -> external C.
// ---------------------------------------------------------------------------
template <int MODE>
__global__ __launch_bounds__(512, 4) void gemm128(
        const short* __restrict__ A, const short* __restrict__ BT,
        const float* __restrict__ bias, void* __restrict__ C,
        int m0g, int Mreal, int N,
        const float* __restrict__ mask, const short* __restrict__ resid,
        const void* __restrict__ hs, const float* __restrict__ flag) {
    constexpr int K = DD;
    constexpr int BK = 64;
    __shared__ __align__(16) short As[128 * BK];   // 16 KB
    __shared__ __align__(16) short Bs[128 * BK];   // 16 KB
    int tiles_n = N >> 7;
    // bijective XCD-aware swizzle (m204)
    int nwg = gridDim.x, bid = blockIdx.x;
    int qq = nwg >> 3, rr = nwg & 7, xcd = bid & 7, lid = bid >> 3;
    int wg = (xcd < rr ? xcd * (qq + 1) : rr * (qq + 1) + (xcd - rr) * qq) + lid;
    int bm = wg / tiles_n, bn = wg % tiles_n;
    int m0 = bm << 7, n0 = bn << 7;

    int tid = threadIdx.x, lane = tid & 63, wave = tid >> 6;   // 8 waves
    int wx = wave & 3, wy = wave >> 2;        // 4 n-waves x 2 m-waves
    int quad = lane >> 4, l16 = lane & 15, l7 = l16 & 7;

    // Staging: each matrix = 1024 16B-slots (128 rows x 8 chunks).
    // Wave w, inst i covers slots [w*128 + i*64, +64): slot s -> row s>>3,
    // chunk s&7; source col = ((s&7) ^ (row&7))*8 shorts (XOR swizzle on the
    // SOURCE side since global_load_lds writes linearly: base + lane*16).
    int slot0 = (wave << 7) + lane;
    int slot1 = slot0 + 64;
    int r0 = slot0 >> 3, c0s = ((slot0 & 7) ^ (r0 & 7)) << 3;
    int r1 = slot1 >> 3, c1s = ((slot1 & 7) ^ (r1 & 7)) << 3;
    int am0 = m0 + r0; if (am0 >= Mreal) am0 = Mreal - 1;
    int am1 = m0 + r1; if (am1 >= Mreal) am1 = Mreal - 1;
    const short* Ag0 = A + (size_t)am0 * K + c0s;
    const short* Ag1 = A + (size_t)am1 * K + c1s;
    const short* Bg0 = BT + (size_t)(n0 + r0) * K + c0s;
    const short* Bg1 = BT + (size_t)(n0 + r1) * K + c1s;
    short* Al0 = As + wave * 1024;             // slot*8 shorts
    short* Al1 = Al0 + 512;
    short* Bl0 = Bs + wave * 1024;
    short* Bl1 = Bl0 + 512;

    floatx4 acc[4][2] = {};
    for (int k0 = 0; k0 < K; k0 += BK) {
        gload_lds16(Ag0 + k0, Al0);
        gload_lds16(Ag1 + k0, Al1);
        gload_lds16(Bg0 + k0, Bl0);
        gload_lds16(Bg1 + k0, Bl1);
        __syncthreads();                       // drains vmcnt before barrier
        #pragma unroll
        for (int ks = 0; ks < 2; ks++) {
            int colo = ((((ks << 2) + quad) ^ l7) << 3);
            short8 af[4], bfr[2];
            #pragma unroll
            for (int i = 0; i < 4; i++)
                af[i] = *(const short8*)&As[(((wy << 6) + (i << 4) + l16) << 6) + colo];
            #pragma unroll
            for (int j = 0; j < 2; j++)
                bfr[j] = *(const short8*)&Bs[(((wx << 5) + (j << 4) + l16) << 6) + colo];
            #pragma unroll
            for (int i = 0; i < 4; i++)
                #pragma unroll
                for (int j = 0; j < 2; j++)
                    acc[i][j] = __builtin_amdgcn_mfma_f32_16x16x32_bf16(
                        af[i], bfr[j], acc[i][j], 0, 0, 0);
        }
        __syncthreads();                       // reads done before next stage
    }

    bool isf32 = (MODE == 1) ? (*flag != 0.f) : false;
    #pragma unroll
    for (int i = 0; i < 4; i++)
        #pragma unroll
        for (int j = 0; j < 2; j++) {
            int n = n0 + (wx << 5) + (j << 4) + l16;
            float bb = bias[n];
            #pragma unroll
            for (int r = 0; r < 4; r++) {
                int m = m0 + (wy << 6) + (i << 4) + (quad << 2) + r;
                if (m >= Mreal) continue;
                float v = acc[i][j][r] + bb;
                if (MODE == 0) {
                    ((short*)C)[(size_t)m * N + n] = f2bf(v);
                } else {
                    size_t gm = (size_t)(m0g + m);
                    v += bf2f(resid[(size_t)m * N + n]);
                    if (mask[gm] == 0.f) v = ldf(hs, gm * N + n, isf32);
                    if (isf32) ((float*)C)[gm * N + n] = v;
                    else       ((short*)C)[gm * N + n] = f2bf(v);
                }
            }
        }
}

// ---------------------------------------------------------------------------
// Attention, in-register P (swapped QK^T): block = (b, h, 64 q-rows),
// wave = 16 q-cols (q = l16). sc = mfma(K, Q) -> lane holds P[k][q=own l16];
// softmax reduces over quad group (xor16+xor32); P packed to bf16 via
// v_cvt_pk_bf16_f32; PV B-fragment assembled by a 6-shfl exchange per
// 32-wide s-tile; O^T = mfma(Vt, P). No P LDS buffer, one barrier total.
// ---------------------------------------------------------------------------
__global__ __launch_bounds__(256) void attn_kernel(
        const short* __restrict__ qkv, short* __restrict__ ctx) {
    __shared__ __align__(16) short Vt[DHD * SPS];      // 29696 B only
    int nwg = gridDim.x, bid = blockIdx.x;
    int qq = nwg >> 3, rr = nwg & 7, xcd = bid & 7, lid = bid >> 3;
    int blk = (xcd < rr ? xcd * (qq + 1) : rr * (qq + 1) + (xcd - rr) * qq) + lid;
    int qc = blk & 3;
    int h  = (blk >> 2) % HN;
    int b  = blk / (4 * HN);
    int tid = threadIdx.x, lane = tid & 63, wave = tid >> 6;
    int quad = lane >> 4, l16 = lane & 15;
    const short* base = qkv + (size_t)b * SQ * 2304;

    for (int i = tid; i < SQ * DHD; i += 256) {
        int s = i >> 6, d = i & 63;
        Vt[d * SPS + s] = base[(size_t)s * 2304 + 1536 + h * 64 + d];
    }
    for (int i = tid; i < (SP - SQ) * DHD; i += 256) {
        int s = SQ + i % (SP - SQ), d = i / (SP - SQ);
        Vt[d * SPS + s] = 0;
    }
    __syncthreads();

    // Q as B-operand: lane's q-col = its own row
    int mrow = qc * 64 + wave * 16 + l16;
    if (mrow > SQ - 1) mrow = SQ - 1;
    const short* Qrow = base + (size_t)mrow * 2304 + h * 64;
    short8 bq0 = *(const short8*)(Qrow + quad * 8);
    short8 bq1 = *(const short8*)(Qrow + 32 + quad * 8);

    // Swapped QK^T: sc[t][r] = S[k = 16t + 4*quad + r][q = l16]
    // t=13 (k>=208) is all-padding -> skipped entirely.
    floatx4 sc[13];
    #pragma unroll
    for (int t = 0; t < 13; t++) {
        int nrow = t * 16 + l16;
        if (nrow > SQ - 1) nrow = SQ - 1;
        const short* Krow = base + (size_t)nrow * 2304 + DD + h * 64;
        short8 ka0 = *(const short8*)(Krow + quad * 8);
        short8 ka1 = *(const short8*)(Krow + 32 + quad * 8);
        floatx4 c = {0.f, 0.f, 0.f, 0.f};
        c = __builtin_amdgcn_mfma_f32_16x16x32_bf16(ka0, bq0, c, 0, 0, 0);
        c = __builtin_amdgcn_mfma_f32_16x16x32_bf16(ka1, bq1, c, 0, 0, 0);
        sc[t] = c;
    }

    // softmax over k (per q-col): t<12 all valid; t=12 valid iff 4q+r<=4
    const float scale = 0.125f;
    float mx = -1e30f;
    #pragma unroll
    for (int t = 0; t < 12; t++)
        #pragma unroll
        for (int r = 0; r < 4; r++) mx = fmaxf(mx, sc[t][r]);
    #pragma unroll
    for (int r = 0; r < 4; r++)
        mx = fmaxf(mx, (4 * quad + r < 5) ? sc[12][r] : -1e30f);
    mx = fmaxf(mx, __shfl_xor(mx, 16, 64));
    mx = fmaxf(mx, __shfl_xor(mx, 32, 64));
    float sum = 0.f;
    #pragma unroll
    for (int t = 0; t < 12; t++)
        #pragma unroll
        for (int r = 0; r < 4; r++) {
            float e = __expf((sc[t][r] - mx) * scale);
            sc[t][r] = e; sum += e;
        }
    #pragma unroll
    for (int r = 0; r < 4; r++) {
        float e = (4 * quad + r < 5) ? __expf((sc[12][r] - mx) * scale) : 0.f;
        sc[12][r] = e; sum += e;
    }
    sum += __shfl_xor(sum, 16, 64);
    sum += __shfl_xor(sum, 32, 64);
    float inv = 1.f / sum;

    // pack P to bf16 pairs: pklo[t] = (r0,r1), pkhi[t] = (r2,r3)
    unsigned pklo[14], pkhi[14];
    #pragma unroll
    for (int t = 0; t < 13; t++) {
        pklo[t] = cvtpk(sc[t][0] * inv, sc[t][1] * inv);
        pkhi[t] = cvtpk(sc[t][2] * inv, sc[t][3] * inv);
    }
    pklo[13] = 0u; pkhi[13] = 0u;

    // PV: O^T[d][q] = mfma(A=Vt tile, B=P fragment). B-frag for lane
    // (q=l16, quad): P[q][s = 32u + 8*quad + j], assembled by quad-group
    // exchange of the packed pairs (verified per-quad mapping).
    int c0 = quad & 1, par = quad >> 1;
    floatx4 co[4] = {};
    #pragma unroll
    for (int u = 0; u < 7; u++) {
        int t0 = 2 * u, t1 = 2 * u + 1;
        unsigned eol = par ? pklo[t1] : pklo[t0];
        unsigned eoh = par ? pkhi[t1] : pkhi[t0];
        unsigned exl = par ? pklo[t0] : pklo[t1];
        unsigned exh = par ? pkhi[t0] : pkhi[t1];
        unsigned a16l = __shfl_xor(eol, 16, 64), a16h = __shfl_xor(eoh, 16, 64);
        unsigned a32l = __shfl_xor(exl, 32, 64), a32h = __shfl_xor(exh, 32, 64);
        unsigned a48l = __shfl_xor(exl, 48, 64), a48h = __shfl_xor(exh, 48, 64);
        uintx4 fw;
        fw[0] = c0 ? (par ? a16l : a48l) : (par ? a32l : eol);
        fw[1] = c0 ? (par ? a16h : a48h) : (par ? a32h : eoh);
        fw[2] = c0 ? (par ? eol : a32l) : (par ? a48l : a16l);
        fw[3] = c0 ? (par ? eoh : a32h) : (par ? a48h : a16h);
        short8 pa = __builtin_bit_cast(short8, fw);
        #pragma unroll
        for (int j = 0; j < 4; j++) {
            short8 vb = *(const short8*)&Vt[(j * 16 + l16) * SPS + u * 32 + quad * 8];
            co[j] = __builtin_amdgcn_mfma_f32_16x16x32_bf16(vb, pa, co[j], 0, 0, 0);
        }
    }

    // write: lane owns q = l16 row; d = 16j + 4*quad + r -> packed 8B stores
    int sq = qc * 64 + wave * 16 + l16;
    if (sq < SQ) {
        size_t o = ((size_t)(b * SQ + sq)) * DD + h * 64;
        #pragma unroll
        for (int j = 0; j < 4; j++) {
            uintx2 w;
            w[0] = cvtpk(co[j][0], co[j][1]);
            w[1] = cvtpk(co[j][2], co[j][3]);
            *reinterpret_cast<uintx2*>(&ctx[o + j * 16 + quad * 4]) = w;
        }
    }
}

// ---------------------------------------------------------------------------
extern "C" void kernel_launch(void* const* d_in, const int* in_sizes, int n_in,
                              void* d_out, int out_size, void* d_ws, size_t ws_size,
                              hipStream_t stream) {
    const void* hs = d_in[0];
    const void* Wq = d_in[1];
    const void* bq = d_in[2];
    const void* Wk = d_in[3];
    const void* bk = d_in[4];
    const void* Wv = d_in[5];
    const void* bv = d_in[6];
    const void* Wd = d_in[7];
    const void* bd = d_in[8];
    const void* W1 = d_in[9];
    const void* b1 = d_in[10];
    const void* W2 = d_in[11];
    const void* b2 = d_in[12];

    const size_t flag_b  = 16;
    const size_t mask_b  = (size_t)TOK * 4;
    const size_t bcat_b  = (size_t)(4 * DD + 192) * 4;
    const size_t wqkvt_b = (size_t)3 * DD * DD * 2;
    const size_t wdt_b   = (size_t)DD * DD * 2;
    const size_t w1t_b   = (size_t)64 * DD * 2;
    const size_t hsb_b   = (size_t)TOK * DD * 2;
    const size_t fixed   = flag_b + mask_b + bcat_b + wqkvt_b + wdt_b + w1t_b + hsb_b;

    int CHB = 0;
    for (int c = 128; c >= 1; c >>= 1) {
        size_t chtp = (size_t)((c * SQ + 127) / 128) * 128;
        size_t need = fixed + chtp * 2304 * 2 + chtp * DD * 2;
        if (need <= ws_size) { CHB = c; break; }
    }
    if (CHB == 0) {
        sentinel_kernel<<<(out_size + 255) / 256, 256, 0, stream>>>(
            (short*)d_out, out_size, (float)((double)ws_size / 1.0e6));
        return;
    }
    const int CHT  = CHB * SQ;
    const int CHTP = ((CHT + 127) / 128) * 128;

    char* ws = (char*)d_ws;
    float* flag  = (float*)ws;
    float* mask  = (float*)(ws + flag_b);
    float* bcat  = (float*)(ws + flag_b + mask_b);
    short* WqkvT = (short*)(ws + flag_b + mask_b + bcat_b);
    short* WdT   = WqkvT + (size_t)3 * DD * DD;
    short* W1T   = WdT + (size_t)DD * DD;
    short* hsb   = W1T + (size_t)64 * DD;
    short* QKVc  = hsb + (size_t)TOK * DD;
    short* ctxc  = QKVc + (size_t)CHTP * 2304;

    detect_kernel<<<1, 256, 0, stream>>>((const short*)Wq, flag);
    prep_kernel<<<588, 256, 0, stream>>>(Wq, Wk, Wv, Wd, bq, bk, bv, bd,
                                         W1, b1, W2, b2,
                                         WqkvT, WdT, W1T, bcat, flag);
    mask_gemm<<<TOK / 64, 256, 0, stream>>>(hs, W1T, bcat, mask, hsb, flag);

    const int nchunk  = BB / CHB;
    const int tiles_m = CHTP / 128;
    for (int c = 0; c < nchunk; c++) {
        const int m0g = c * CHT;
        gemm128<0><<<tiles_m * (3 * DD / 128), 512, 0, stream>>>(
            hsb + (size_t)m0g * DD, WqkvT, bcat, QKVc,
            m0g, CHT, 3 * DD, nullptr, nullptr, nullptr, flag);
        attn_kernel<<<CHB * HN * 4, 256, 0, stream>>>(QKVc, ctxc);
        gemm128<1><<<tiles_m * (DD / 128), 512, 0, stream>>>(
            ctxc, WdT, bcat + 3 * DD, d_out,
            m0g, CHT, DD, mask, ctxc, hs, flag);
    }
}